// Round 4
// baseline (476.376 us; speedup 1.0000x reference)
//
#include <hip/hip_runtime.h>
#include <hip/hip_bf16.h>
#include <stdint.h>

// Problem constants
#define BB 4
#define NN 2048
#define DIMD 512
#define HH 8
#define DKK 64
#define MTOT (BB * NN)          // 8192
constexpr float SCALE = 0.125f;       // DK^-0.5
constexpr float L2E = 1.44269504089f; // log2(e)

typedef __attribute__((ext_vector_type(4))) float f32x4;
typedef __attribute__((ext_vector_type(2))) float f32x2;
typedef __attribute__((ext_vector_type(8))) short bf16x8;   // 8 bf16 (4 VGPRs)
typedef __attribute__((ext_vector_type(4))) _Float16 f16x4; // 4 f16 (2 VGPRs)
typedef __attribute__((ext_vector_type(2))) __fp16 fp16v2;  // cvt_pkrtz result
typedef __attribute__((ext_vector_type(4))) __fp16 fp16v4;
typedef __attribute__((ext_vector_type(2))) unsigned int u32x2;

union pack8 { unsigned short s[8]; uint4 v; };
union fragu { u32x2 h[2]; bf16x8 v; };

__device__ __forceinline__ unsigned short f2bf(float f) {
  union { float f; uint32_t u; } v; v.f = f;
  uint32_t u = v.u;
  return (unsigned short)((u + 0x7FFFu + ((u >> 16) & 1u)) >> 16); // RNE
}

__device__ __forceinline__ unsigned short f2h(float f) {
  union { _Float16 h; unsigned short u; } c; c.h = (_Float16)f;
  return c.u;
}

// LDS helpers for stride-68 (8B-aligned) rows: explicit b64 ops
__device__ __forceinline__ bf16x8 ld_frag(const unsigned short* p) {
  fragu f;
  f.h[0] = *(const u32x2*)p;
  f.h[1] = *(const u32x2*)(p + 4);
  return f.v;
}
__device__ __forceinline__ void st8(unsigned short* p, uint4 v) {
  *(u32x2*)p = (u32x2){v.x, v.y};
  *(u32x2*)(p + 4) = (u32x2){v.z, v.w};
}

// Input sv is PRE-SCALED by log2(e) (done in qk_gemm epilogue), so
// e = 2^(-|sv|) = exp(-|x|) is a single v_exp_f32 with -abs modifiers.
// Returns sigmoid(x) - 0.5 packed to f16 (the +0.5 term is pre-filled
// into out as 0.5*rowsum(V) by qk_gemm's prefill blocks).
__device__ __forceinline__ f16x4 sig_pack(f32x4 sv) {
  float e0 = __builtin_amdgcn_exp2f(-__builtin_fabsf(sv[0]));
  float e1 = __builtin_amdgcn_exp2f(-__builtin_fabsf(sv[1]));
  float e2 = __builtin_amdgcn_exp2f(-__builtin_fabsf(sv[2]));
  float e3 = __builtin_amdgcn_exp2f(-__builtin_fabsf(sv[3]));
  const f32x2 c3 = {-0.22184f, -0.22184f};
  const f32x2 c2 = {0.66550f, 0.66550f};
  const f32x2 c1 = {-0.94280f, -0.94280f};
  const f32x2 c0 = {0.49826f, 0.49826f};
  f32x2 eA = {e0, e1}, eB = {e2, e3};
  f32x2 pA = __builtin_elementwise_fma(
      __builtin_elementwise_fma(__builtin_elementwise_fma(c3, eA, c2), eA, c1),
      eA, c0);
  f32x2 pB = __builtin_elementwise_fma(
      __builtin_elementwise_fma(__builtin_elementwise_fma(c3, eB, c2), eB, c1),
      eB, c0);
  float r0 = __builtin_copysignf(pA.x, sv[0]);
  float r1 = __builtin_copysignf(pA.y, sv[1]);
  float r2 = __builtin_copysignf(pB.x, sv[2]);
  float r3 = __builtin_copysignf(pB.y, sv[3]);
  fp16v2 lo = __builtin_amdgcn_cvt_pkrtz(r0, r1);
  fp16v2 hi = __builtin_amdgcn_cvt_pkrtz(r2, r3);
  fp16v4 p;
  p.x = lo.x; p.y = lo.y; p.z = hi.x; p.w = hi.y;
  return __builtin_bit_cast(f16x4, p);
}

// ---------------------------------------------------------------------------
// prep (fused):
//   blocks [0,2048):    xb bf16 [B*N][DIM] — streaming convert
//   blocks [2048,2304): xtf f16 [B][DIM][N] — transpose; reduces per-block
//                       V-partials into vsum_p[b][nt][d] (race-free).
//   blocks [2304,2432): Wq/Wk -> Wt bf16 [N][K] via stride-68 LDS tile
// ---------------------------------------------------------------------------
__global__ __launch_bounds__(256) void prep(const float* __restrict__ x,
                                            const float* __restrict__ wq,
                                            const float* __restrict__ wk,
                                            unsigned short* __restrict__ xb,
                                            unsigned short* __restrict__ xtf,
                                            unsigned short* __restrict__ wtq,
                                            unsigned short* __restrict__ wtk,
                                            float* __restrict__ vsum_p) {
  const int bx = blockIdx.x, tid = threadIdx.x;
  if (bx < 2048) {
    size_t base = ((size_t)bx * 256 + tid) * 8;
    float4 a = *(const float4*)(x + base);
    float4 b = *(const float4*)(x + base + 4);
    pack8 p;
    p.s[0] = f2bf(a.x); p.s[1] = f2bf(a.y); p.s[2] = f2bf(a.z); p.s[3] = f2bf(a.w);
    p.s[4] = f2bf(b.x); p.s[5] = f2bf(b.y); p.s[6] = f2bf(b.z); p.s[7] = f2bf(b.w);
    *(uint4*)(xb + base) = p.v;
  } else if (bx < 2304) {
    __shared__ float Pred[4][64];
    int q = bx - 2048;
    int b = q >> 6, r = q & 63;
    int dt = r >> 3, nt = r & 7;
    int dl = tid & 63, c = tid >> 6;
    int d = dt * 64 + dl;
    int n0 = nt * 256 + c * 64;
    const float* xp = x + ((size_t)b * NN + n0) * DIMD + d;
    unsigned short* dp = xtf + ((size_t)b * DIMD + d) * NN + n0;
    float s = 0.f;
#pragma unroll
    for (int g = 0; g < 8; g++) {
      pack8 pa;
#pragma unroll
      for (int k = 0; k < 8; k++) {
        float v = xp[(size_t)(g * 8 + k) * DIMD];
        s += v;
        pa.s[k] = f2h(v);
      }
      *(uint4*)(dp + g * 8) = pa.v;
    }
    Pred[c][dl] = s;
    __syncthreads();
    if (c == 0) {
      float t = Pred[0][dl] + Pred[1][dl] + Pred[2][dl] + Pred[3][dl];
      vsum_p[((size_t)b * 8 + nt) * DIMD + d] = t;
    }
  } else {
    __shared__ __align__(16) unsigned short T[64][68];
    int q = bx - 2304;
    const float* w = (q >= 64) ? wk : wq;
    unsigned short* wt = (q >= 64) ? wtk : wtq;
    int r = q & 63;
    int kt = r >> 3, nt = r & 7;
    const int k0 = kt * 64, n0 = nt * 64;
#pragma unroll
    for (int rr = 0; rr < 16; rr++) {
      int idx = tid + rr * 256;
      int kl = idx >> 6, nl = idx & 63;
      T[nl][kl] = f2bf(w[(size_t)(k0 + kl) * DIMD + n0 + nl]);
    }
    __syncthreads();
#pragma unroll
    for (int rr = 0; rr < 2; rr++) {
      int idx = tid + rr * 256;
      int nl = idx >> 3, c = idx & 7;
      fragu f;
      f.h[0] = *(const u32x2*)&T[nl][c * 8];
      f.h[1] = *(const u32x2*)&T[nl][c * 8 + 4];
      uint4 v;
      v.x = f.h[0].x; v.y = f.h[0].y; v.z = f.h[1].x; v.w = f.h[1].y;
      *(uint4*)(wt + (size_t)(n0 + nl) * DIMD + k0 + c * 8) = v;
    }
  }
}

// ---------------------------------------------------------------------------
// qk_gemm: 128x128 tile (proven best), 512 threads = 8 waves (2wm x 4wn),
//   register prefetch. Q output pre-scaled by log2(e) for the exp2 sigmoid.
//   NEW: nb in [8,12) = 256 PREFILL blocks: out[b][n][:] = 0.5*rowsum(V)
//   (sum of prep's 8 partials) — attn then atomicAdds its partial O on top.
// ---------------------------------------------------------------------------
__global__ __launch_bounds__(512, 4) void qk_gemm(const unsigned short* __restrict__ xb,
                                                  const unsigned short* __restrict__ wtq,
                                                  const unsigned short* __restrict__ wtk,
                                                  const float* __restrict__ bias,
                                                  const float* __restrict__ vsum_p,
                                                  unsigned short* __restrict__ qout,
                                                  unsigned short* __restrict__ kout,
                                                  float* __restrict__ out) {
  __shared__ __align__(16) unsigned short Als[128][68];
  __shared__ __align__(16) unsigned short Bls[128][68];
  const int mb = blockIdx.x, nb = blockIdx.y;
  const int tid = threadIdx.x;

  if (nb >= 8) {
    // ---- prefill: 32 rows of out = 0.5 * rowsum(V) ----
    float* sred = (float*)Als; // 512 f32
    const int row0 = mb * 128 + (nb - 8) * 32;
    const int b = row0 >> 11;
    {
      float s = 0.f;
#pragma unroll
      for (int p = 0; p < 8; p++) s += vsum_p[((size_t)b * 8 + p) * DIMD + tid];
      sred[tid] = 0.5f * s;
    }
    __syncthreads();
    const int n_l = tid >> 4, dc = (tid & 15) * 32;
    float* op = out + (size_t)(row0 + n_l) * DIMD + dc;
#pragma unroll
    for (int g = 0; g < 8; g++) {
      f32x4 v = *(const f32x4*)&sred[dc + g * 4];
      *(f32x4*)(op + g * 4) = v;
    }
    return;
  }

  const bool isQ = (nb < 4);
  const unsigned short* wt = isQ ? wtq : wtk;
  unsigned short* outp = isQ ? qout : kout;
  const int n0 = (nb & 3) * 128, m0 = mb * 128;
  const int wave = tid >> 6, lane = tid & 63;
  const int quad = lane >> 4, l16 = lane & 15;
  const int wm = wave >> 2, wn = wave & 3;

  f32x4 acc[4][2];
#pragma unroll
  for (int a = 0; a < 4; a++)
#pragma unroll
    for (int c = 0; c < 2; c++) acc[a][c] = (f32x4){0.f, 0.f, 0.f, 0.f};

  const int srow[2] = {tid >> 3, (tid + 512) >> 3};
  const int scol = (tid & 7) * 8;
  uint4 pa[2], pb[2];
#pragma unroll
  for (int r = 0; r < 2; r++) {
    pa[r] = *(const uint4*)(xb + (size_t)(m0 + srow[r]) * DIMD + scol);
    pb[r] = *(const uint4*)(wt + (size_t)(n0 + srow[r]) * DIMD + scol);
  }

  for (int k0 = 0; k0 < DIMD; k0 += 64) {
    __syncthreads();
#pragma unroll
    for (int r = 0; r < 2; r++) {
      st8(&Als[srow[r]][scol], pa[r]);
      st8(&Bls[srow[r]][scol], pb[r]);
    }
    __syncthreads();
    if (k0 + 64 < DIMD) {
#pragma unroll
      for (int r = 0; r < 2; r++) {
        pa[r] = *(const uint4*)(xb + (size_t)(m0 + srow[r]) * DIMD + k0 + 64 + scol);
        pb[r] = *(const uint4*)(wt + (size_t)(n0 + srow[r]) * DIMD + k0 + 64 + scol);
      }
    }
#pragma unroll
    for (int ks = 0; ks < 2; ks++) {
      bf16x8 af[4], bfr[2];
#pragma unroll
      for (int t = 0; t < 4; t++)
        af[t] = ld_frag(&Als[wm * 64 + t * 16 + l16][quad * 8 + ks * 32]);
#pragma unroll
      for (int t = 0; t < 2; t++)
        bfr[t] = ld_frag(&Bls[wn * 32 + t * 16 + l16][quad * 8 + ks * 32]);
#pragma unroll
      for (int tm = 0; tm < 4; tm++)
#pragma unroll
        for (int tn = 0; tn < 2; tn++)
          acc[tm][tn] =
              __builtin_amdgcn_mfma_f32_16x16x32_bf16(af[tm], bfr[tn], acc[tm][tn], 0, 0, 0);
    }
  }
#pragma unroll
  for (int tm = 0; tm < 4; tm++) {
#pragma unroll
    for (int tn = 0; tn < 2; tn++) {
      int gcol = n0 + wn * 32 + tn * 16 + l16;
      float bl = isQ ? bias[gcol] * L2E : 0.f;
#pragma unroll
      for (int r = 0; r < 4; r++) {
        int row = m0 + wm * 64 + tm * 16 + quad * 4 + r;
        float v = acc[tm][tn][r];
        if (isQ) v = v * (SCALE * L2E) + bl;
        outp[(size_t)row * DIMD + gcol] = f2bf(v);
      }
    }
  }
}

// ---------------------------------------------------------------------------
// attn: O_partial = (sigmoid(Q K^T)-0.5) V, atomicAdd'ed into the prefilled
//   out (= 0.5*rowsum(V)). Geometry: BM=128, 512 thr = 2 j-groups x 4 waves,
//   wave = 2 i-subtiles (per-wave amortization identical to the 68-us R0/R2
//   structure). NEW: j-range SPLIT across blockIdx.z (each block does 1024 j,
//   8 iters/group) -> grid (32,16,2)=1024 blocks = 4 blocks/CU (was 2,
//   grid-limited). Single-buffered LDS 34.8 KB (dbuf measured neutral, R3);
//   __launch_bounds__(512,8) pins 4 blocks/CU. XCD swizzle: id%8 == bh%8.
// ---------------------------------------------------------------------------
__global__ __launch_bounds__(512, 8) void attn(const unsigned short* __restrict__ qb,
                                               const unsigned short* __restrict__ kb,
                                               const unsigned short* __restrict__ xtf,
                                               float* __restrict__ out) {
  __shared__ __align__(16) char smem[34816];
  unsigned short* Kall = (unsigned short*)smem;    // [2][64][68]
  unsigned short* Vall = Kall + 2 * 64 * 68;       // [2][64][68]
  float* R0 = (float*)smem;                        // [128][66] combine (reused)

  const int bh = blockIdx.x, it = blockIdx.y, jh = blockIdx.z;
  const int b = bh >> 3, h = bh & 7;
  const int i0 = it * 128;
  const int tid = threadIdx.x;
  const int lane = tid & 63;
  const int grp = tid >> 8;          // j-group 0/1
  const int wv = (tid >> 6) & 3;     // wave within group
  const int gtid = tid & 255;
  const int quad = lane >> 4, l16 = lane & 15;

  // Q B-fragments for 2 i-subtiles
  bf16x8 qf[2][2];
  int irow[2];
#pragma unroll
  for (int s_ = 0; s_ < 2; s_++) {
    irow[s_] = i0 + wv * 32 + s_ * 16 + l16;
    const unsigned short* qp = qb + ((size_t)b * NN + irow[s_]) * DIMD + h * DKK + quad * 8;
    qf[s_][0] = *(const bf16x8*)qp;
    qf[s_][1] = *(const bf16x8*)(qp + 32);
  }

  f32x4 o[2][4];
#pragma unroll
  for (int s_ = 0; s_ < 2; s_++)
#pragma unroll
    for (int td = 0; td < 4; td++) o[s_][td] = (f32x4){0.f, 0.f, 0.f, 0.f};

  const unsigned short* kbase = kb + (size_t)b * NN * DIMD + h * DKK;
  const unsigned short* vbase = xtf + ((size_t)b * DIMD + h * DKK) * NN;
  unsigned short* Kg = Kall + grp * (64 * 68);
  unsigned short* Vg = Vall + grp * (64 * 68);
  const int jbase = jh * 1024 + grp * 512;

  const int trow[2] = {gtid >> 3, (gtid + 256) >> 3};
  const int tcol = (gtid & 7) * 8;
  uint4 pk[2], pv[2];

  {
    const int j0 = jbase;
#pragma unroll
    for (int r = 0; r < 2; r++) {
      pk[r] = *(const uint4*)(kbase + (size_t)(j0 + trow[r]) * DIMD + tcol);
      pv[r] = *(const uint4*)(vbase + (size_t)trow[r] * NN + j0 + tcol);
    }
  }

  for (int itr = 0; itr < 8; itr++) {
    __syncthreads();
#pragma unroll
    for (int r = 0; r < 2; r++) {
      st8(&Kg[trow[r] * 68 + tcol], pk[r]);
      st8(&Vg[trow[r] * 68 + tcol], pv[r]);
    }
    __syncthreads();
    if (itr < 7) {
      const int j0 = jbase + (itr + 1) * 64;
#pragma unroll
      for (int r = 0; r < 2; r++) {
        pk[r] = *(const uint4*)(kbase + (size_t)(j0 + trow[r]) * DIMD + tcol);
        pv[r] = *(const uint4*)(vbase + (size_t)trow[r] * NN + j0 + tcol);
      }
    }

    __builtin_amdgcn_s_setprio(1);
#pragma unroll
    for (int t = 0; t < 4; t++) {
      bf16x8 kf0 = ld_frag(&Kg[(t * 16 + l16) * 68 + quad * 8]);
      bf16x8 kf1 = ld_frag(&Kg[(t * 16 + l16) * 68 + quad * 8 + 32]);
      f16x4 pf[2];
#pragma unroll
      for (int s_ = 0; s_ < 2; s_++) {
        f32x4 sv = (f32x4){0.f, 0.f, 0.f, 0.f};
        sv = __builtin_amdgcn_mfma_f32_16x16x32_bf16(kf0, qf[s_][0], sv, 0, 0, 0);
        sv = __builtin_amdgcn_mfma_f32_16x16x32_bf16(kf1, qf[s_][1], sv, 0, 0, 0);
        pf[s_] = sig_pack(sv);
      }
#pragma unroll
      for (int td = 0; td < 4; td++) {
        f16x4 vf = __builtin_bit_cast(
            f16x4, *(const u32x2*)&Vg[(td * 16 + l16) * 68 + t * 16 + quad * 4]);
        o[0][td] = __builtin_amdgcn_mfma_f32_16x16x16f16(vf, pf[0], o[0][td], 0, 0, 0);
        o[1][td] = __builtin_amdgcn_mfma_f32_16x16x16f16(vf, pf[1], o[1][td], 0, 0, 0);
      }
    }
    __builtin_amdgcn_s_setprio(0);
  }

  // combine the two j-groups' partial O^T through LDS; group 0 atomicAdds
  // into the prefilled out.
  __syncthreads();
  if (grp == 1) {
#pragma unroll
    for (int s_ = 0; s_ < 2; s_++)
#pragma unroll
      for (int td = 0; td < 4; td++) {
        int base = (wv * 32 + s_ * 16 + l16) * 66 + td * 16 + quad * 4;
        *(f32x2*)&R0[base] = (f32x2){o[s_][td][0], o[s_][td][1]};
        *(f32x2*)&R0[base + 2] = (f32x2){o[s_][td][2], o[s_][td][3]};
      }
  }
  __syncthreads();
  if (grp == 0) {
#pragma unroll
    for (int s_ = 0; s_ < 2; s_++) {
#pragma unroll
      for (int td = 0; td < 4; td++) {
        int base = (wv * 32 + s_ * 16 + l16) * 66 + td * 16 + quad * 4;
        f32x2 a = *(const f32x2*)&R0[base];
        f32x2 c = *(const f32x2*)&R0[base + 2];
        float v0 = o[s_][td][0] + a.x;
        float v1 = o[s_][td][1] + a.y;
        float v2 = o[s_][td][2] + c.x;
        float v3 = o[s_][td][3] + c.y;
        float* op = out + ((size_t)b * NN + irow[s_]) * DIMD + h * DKK + td * 16 + quad * 4;
        atomicAdd(op + 0, v0);
        atomicAdd(op + 1, v1);
        atomicAdd(op + 2, v2);
        atomicAdd(op + 3, v3);
      }
    }
  }
}

// ---------------------------------------------------------------------------
extern "C" void kernel_launch(void* const* d_in, const int* in_sizes, int n_in,
                              void* d_out, int out_size, void* d_ws, size_t ws_size,
                              hipStream_t stream) {
  const float* x = (const float*)d_in[0];
  const float* Wq = (const float*)d_in[1];
  const float* Wk = (const float*)d_in[2];
  const float* bias = (const float*)d_in[3]; // [1,8,1,64] flat = 512
  float* out = (float*)d_out;

  unsigned short* ws = (unsigned short*)d_ws;
  unsigned short* xb = ws;                         // 4,194,304
  unsigned short* xtf = xb + (size_t)MTOT * DIMD;  // 4,194,304 (f16 bits)
  unsigned short* wtq = xtf + (size_t)MTOT * DIMD; // 262,144
  unsigned short* wtk = wtq + (size_t)DIMD * DIMD; // 262,144
  unsigned short* qb = wtk + (size_t)DIMD * DIMD;  // 4,194,304
  unsigned short* kb = qb + (size_t)MTOT * DIMD;   // 4,194,304
  float* vsum_p = (float*)(kb + (size_t)MTOT * DIMD); // [4][8][512] f32 = 64 KB

  prep<<<dim3(2432), 256, 0, stream>>>(x, Wq, Wk, xb, xtf, wtq, wtk, vsum_p);
  qk_gemm<<<dim3(64, 12), 512, 0, stream>>>(xb, wtq, wtk, bias, vsum_p, qb, kb, out);
  attn<<<dim3(32, 16, 2), 512, 0, stream>>>(qb, kb, xtf, out);
}

// Round 5
// 150.287 us; speedup vs baseline: 3.1698x; 3.1698x over previous
//
#include <hip/hip_runtime.h>
#include <hip/hip_bf16.h>
#include <stdint.h>

// Problem constants
#define BB 4
#define NN 2048
#define DIMD 512
#define HH 8
#define DKK 64
#define MTOT (BB * NN)          // 8192
constexpr float SCALE = 0.125f;       // DK^-0.5
constexpr float L2E = 1.44269504089f; // log2(e)

typedef __attribute__((ext_vector_type(4))) float f32x4;
typedef __attribute__((ext_vector_type(2))) float f32x2;
typedef __attribute__((ext_vector_type(8))) short bf16x8;   // 8 bf16 (4 VGPRs)
typedef __attribute__((ext_vector_type(4))) _Float16 f16x4; // 4 f16 (2 VGPRs)
typedef __attribute__((ext_vector_type(2))) __fp16 fp16v2;  // cvt_pkrtz result
typedef __attribute__((ext_vector_type(4))) __fp16 fp16v4;
typedef __attribute__((ext_vector_type(2))) unsigned int u32x2;

union pack8 { unsigned short s[8]; uint4 v; };
union fragu { u32x2 h[2]; bf16x8 v; };

__device__ __forceinline__ unsigned short f2bf(float f) {
  union { float f; uint32_t u; } v; v.f = f;
  uint32_t u = v.u;
  return (unsigned short)((u + 0x7FFFu + ((u >> 16) & 1u)) >> 16); // RNE
}

__device__ __forceinline__ unsigned short f2h(float f) {
  union { _Float16 h; unsigned short u; } c; c.h = (_Float16)f;
  return c.u;
}

// LDS helpers for stride-68 (8B-aligned) rows: explicit b64 ops
__device__ __forceinline__ bf16x8 ld_frag(const unsigned short* p) {
  fragu f;
  f.h[0] = *(const u32x2*)p;
  f.h[1] = *(const u32x2*)(p + 4);
  return f.v;
}
__device__ __forceinline__ void st8(unsigned short* p, uint4 v) {
  *(u32x2*)p = (u32x2){v.x, v.y};
  *(u32x2*)(p + 4) = (u32x2){v.z, v.w};
}

// Input sv is PRE-SCALED by log2(e) (folded into qk_gemm epilogue), so
// e = 2^(-|sv|) = exp(-|x|) is one v_exp_f32 with -abs input modifiers.
// Returns sigmoid(x) - 0.5 packed to f16 (the +0.5 term = 0.5*rowsum(V),
// added from vsum_p in the attn epilogue).
__device__ __forceinline__ f16x4 sig_pack(f32x4 sv) {
  float e0 = __builtin_amdgcn_exp2f(-__builtin_fabsf(sv[0]));
  float e1 = __builtin_amdgcn_exp2f(-__builtin_fabsf(sv[1]));
  float e2 = __builtin_amdgcn_exp2f(-__builtin_fabsf(sv[2]));
  float e3 = __builtin_amdgcn_exp2f(-__builtin_fabsf(sv[3]));
  const f32x2 c3 = {-0.22184f, -0.22184f};
  const f32x2 c2 = {0.66550f, 0.66550f};
  const f32x2 c1 = {-0.94280f, -0.94280f};
  const f32x2 c0 = {0.49826f, 0.49826f};
  f32x2 eA = {e0, e1}, eB = {e2, e3};
  f32x2 pA = __builtin_elementwise_fma(
      __builtin_elementwise_fma(__builtin_elementwise_fma(c3, eA, c2), eA, c1),
      eA, c0);
  f32x2 pB = __builtin_elementwise_fma(
      __builtin_elementwise_fma(__builtin_elementwise_fma(c3, eB, c2), eB, c1),
      eB, c0);
  float r0 = __builtin_copysignf(pA.x, sv[0]);
  float r1 = __builtin_copysignf(pA.y, sv[1]);
  float r2 = __builtin_copysignf(pB.x, sv[2]);
  float r3 = __builtin_copysignf(pB.y, sv[3]);
  fp16v2 lo = __builtin_amdgcn_cvt_pkrtz(r0, r1);
  fp16v2 hi = __builtin_amdgcn_cvt_pkrtz(r2, r3);
  fp16v4 p;
  p.x = lo.x; p.y = lo.y; p.z = hi.x; p.w = hi.y;
  return __builtin_bit_cast(f16x4, p);
}

// ---------------------------------------------------------------------------
// prep (xb pass ELIMINATED — qk_gemm now converts x f32->bf16 in its
// prefetch shadow; saves 16 MB read + 8 MB write of HBM and 2048 blocks):
//   blocks [0,256):   xtf f16 [B][DIM][N] — transpose; reduces per-block
//                     V-partials into vsum_p[b][nt][d] (race-free).
//   blocks [256,384): Wq/Wk -> Wt bf16 [N][K] via stride-68 LDS tile
// ---------------------------------------------------------------------------
__global__ __launch_bounds__(256) void prep(const float* __restrict__ x,
                                            const float* __restrict__ wq,
                                            const float* __restrict__ wk,
                                            unsigned short* __restrict__ xtf,
                                            unsigned short* __restrict__ wtq,
                                            unsigned short* __restrict__ wtk,
                                            float* __restrict__ vsum_p) {
  const int bx = blockIdx.x, tid = threadIdx.x;
  if (bx < 256) {
    __shared__ float Pred[4][64];
    int q = bx;
    int b = q >> 6, r = q & 63;
    int dt = r >> 3, nt = r & 7;
    int dl = tid & 63, c = tid >> 6;
    int d = dt * 64 + dl;
    int n0 = nt * 256 + c * 64;
    const float* xp = x + ((size_t)b * NN + n0) * DIMD + d;
    unsigned short* dp = xtf + ((size_t)b * DIMD + d) * NN + n0;
    float s = 0.f;
#pragma unroll
    for (int g = 0; g < 8; g++) {
      pack8 pa;
#pragma unroll
      for (int k = 0; k < 8; k++) {
        float v = xp[(size_t)(g * 8 + k) * DIMD];
        s += v;
        pa.s[k] = f2h(v);
      }
      *(uint4*)(dp + g * 8) = pa.v;
    }
    Pred[c][dl] = s;
    __syncthreads();
    if (c == 0) {
      float t = Pred[0][dl] + Pred[1][dl] + Pred[2][dl] + Pred[3][dl];
      vsum_p[((size_t)b * 8 + nt) * DIMD + d] = t;
    }
  } else {
    __shared__ __align__(16) unsigned short T[64][68];
    int q = bx - 256;
    const float* w = (q >= 64) ? wk : wq;
    unsigned short* wt = (q >= 64) ? wtk : wtq;
    int r = q & 63;
    int kt = r >> 3, nt = r & 7;
    const int k0 = kt * 64, n0 = nt * 64;
#pragma unroll
    for (int rr = 0; rr < 16; rr++) {
      int idx = tid + rr * 256;
      int kl = idx >> 6, nl = idx & 63;
      T[nl][kl] = f2bf(w[(size_t)(k0 + kl) * DIMD + n0 + nl]);
    }
    __syncthreads();
#pragma unroll
    for (int rr = 0; rr < 2; rr++) {
      int idx = tid + rr * 256;
      int nl = idx >> 3, c = idx & 7;
      fragu f;
      f.h[0] = *(const u32x2*)&T[nl][c * 8];
      f.h[1] = *(const u32x2*)&T[nl][c * 8 + 4];
      uint4 v;
      v.x = f.h[0].x; v.y = f.h[0].y; v.z = f.h[1].x; v.w = f.h[1].y;
      *(uint4*)(wt + (size_t)(n0 + nl) * DIMD + k0 + c * 8) = v;
    }
  }
}

// ---------------------------------------------------------------------------
// qk_gemm: 128x128 tile (proven best), 512 threads = 8 waves (2wm x 4wn),
//   register prefetch. NEW: A-operand loaded directly from f32 x; f2bf
//   conversion happens at PREFETCH time (in the MFMA shadow), so the
//   barrier-critical st8 path is identical to the proven R0 loop.
//   Q output pre-scaled by log2(e) for the exp2 sigmoid.
// ---------------------------------------------------------------------------
__global__ __launch_bounds__(512, 4) void qk_gemm(const float* __restrict__ x,
                                                  const unsigned short* __restrict__ wtq,
                                                  const unsigned short* __restrict__ wtk,
                                                  const float* __restrict__ bias,
                                                  unsigned short* __restrict__ qout,
                                                  unsigned short* __restrict__ kout) {
  __shared__ __align__(16) unsigned short Als[128][68];
  __shared__ __align__(16) unsigned short Bls[128][68];
  const int mb = blockIdx.x, nb = blockIdx.y;
  const bool isQ = (nb < 4);
  const unsigned short* wt = isQ ? wtq : wtk;
  unsigned short* outp = isQ ? qout : kout;
  const int n0 = (nb & 3) * 128, m0 = mb * 128;
  const int tid = threadIdx.x;
  const int wave = tid >> 6, lane = tid & 63;
  const int quad = lane >> 4, l16 = lane & 15;
  const int wm = wave >> 2, wn = wave & 3;

  f32x4 acc[4][2];
#pragma unroll
  for (int a = 0; a < 4; a++)
#pragma unroll
    for (int c = 0; c < 2; c++) acc[a][c] = (f32x4){0.f, 0.f, 0.f, 0.f};

  const int srow[2] = {tid >> 3, (tid + 512) >> 3};
  const int scol = (tid & 7) * 8;
  uint4 pa[2], pb[2];

  auto loadA = [&](int r, int k0) -> uint4 {
    const float* ap = x + (size_t)(m0 + srow[r]) * DIMD + k0 + scol;
    float4 a = *(const float4*)ap;
    float4 b = *(const float4*)(ap + 4);
    pack8 p;
    p.s[0] = f2bf(a.x); p.s[1] = f2bf(a.y); p.s[2] = f2bf(a.z); p.s[3] = f2bf(a.w);
    p.s[4] = f2bf(b.x); p.s[5] = f2bf(b.y); p.s[6] = f2bf(b.z); p.s[7] = f2bf(b.w);
    return p.v;
  };

#pragma unroll
  for (int r = 0; r < 2; r++) {
    pa[r] = loadA(r, 0);
    pb[r] = *(const uint4*)(wt + (size_t)(n0 + srow[r]) * DIMD + scol);
  }

  for (int k0 = 0; k0 < DIMD; k0 += 64) {
    __syncthreads();
#pragma unroll
    for (int r = 0; r < 2; r++) {
      st8(&Als[srow[r]][scol], pa[r]);
      st8(&Bls[srow[r]][scol], pb[r]);
    }
    __syncthreads();
    if (k0 + 64 < DIMD) {
#pragma unroll
      for (int r = 0; r < 2; r++) {
        pa[r] = loadA(r, k0 + 64);
        pb[r] = *(const uint4*)(wt + (size_t)(n0 + srow[r]) * DIMD + k0 + 64 + scol);
      }
    }
#pragma unroll
    for (int ks = 0; ks < 2; ks++) {
      bf16x8 af[4], bfr[2];
#pragma unroll
      for (int t = 0; t < 4; t++)
        af[t] = ld_frag(&Als[wm * 64 + t * 16 + l16][quad * 8 + ks * 32]);
#pragma unroll
      for (int t = 0; t < 2; t++)
        bfr[t] = ld_frag(&Bls[wn * 32 + t * 16 + l16][quad * 8 + ks * 32]);
#pragma unroll
      for (int tm = 0; tm < 4; tm++)
#pragma unroll
        for (int tn = 0; tn < 2; tn++)
          acc[tm][tn] =
              __builtin_amdgcn_mfma_f32_16x16x32_bf16(af[tm], bfr[tn], acc[tm][tn], 0, 0, 0);
    }
  }
#pragma unroll
  for (int tm = 0; tm < 4; tm++) {
#pragma unroll
    for (int tn = 0; tn < 2; tn++) {
      int gcol = n0 + wn * 32 + tn * 16 + l16;
      float bl = isQ ? bias[gcol] * L2E : 0.f;
#pragma unroll
      for (int r = 0; r < 4; r++) {
        int row = m0 + wm * 64 + tm * 16 + quad * 4 + r;
        float v = acc[tm][tn][r];
        if (isQ) v = v * (SCALE * L2E) + bl;
        outp[(size_t)row * DIMD + gcol] = f2bf(v);
      }
    }
  }
}

// ---------------------------------------------------------------------------
// attn: O = (sigmoid(Q K^T)-0.5) V + 0.5*rowsum(V). RESTORED to the proven
//   66.3-us R2 structure: BM=128, 512 thr = 2 j-groups x 4 waves, wave = 2
//   i-subtiles, single-buffered LDS 34.8 KB, 2 barriers/j-tile, register
//   prefetch, setprio around compute, grid (bh, it) so id%8 == bh%8 (XCD-
//   local K/V; FETCH 70->12 MB measured in R2). Epilogue sums prep's 8
//   race-free vsum partials (no atomics, no memset — R4's atomic path was
//   a 6x regression, never again).
// ---------------------------------------------------------------------------
__global__ __launch_bounds__(512, 4) void attn(const unsigned short* __restrict__ qb,
                                               const unsigned short* __restrict__ kb,
                                               const unsigned short* __restrict__ xtf,
                                               const float* __restrict__ vsum_p,
                                               float* __restrict__ out) {
  __shared__ __align__(16) char smem[34816];
  unsigned short* Kall = (unsigned short*)smem;    // [2][64][68]
  unsigned short* Vall = Kall + 2 * 64 * 68;       // [2][64][68]
  float* R0 = (float*)smem;                        // [128][66] combine (reused)

  const int bh = blockIdx.x, it = blockIdx.y;      // transposed grid (XCD swizzle)
  const int b = bh >> 3, h = bh & 7;
  const int i0 = it * 128;
  const int tid = threadIdx.x;
  const int lane = tid & 63;
  const int grp = tid >> 8;          // j-group 0/1
  const int wv = (tid >> 6) & 3;     // wave within group
  const int gtid = tid & 255;
  const int quad = lane >> 4, l16 = lane & 15;

  // Q B-fragments for 2 i-subtiles
  bf16x8 qf[2][2];
  int irow[2];
#pragma unroll
  for (int s_ = 0; s_ < 2; s_++) {
    irow[s_] = i0 + wv * 32 + s_ * 16 + l16;
    const unsigned short* qp = qb + ((size_t)b * NN + irow[s_]) * DIMD + h * DKK + quad * 8;
    qf[s_][0] = *(const bf16x8*)qp;
    qf[s_][1] = *(const bf16x8*)(qp + 32);
  }

  f32x4 o[2][4];
#pragma unroll
  for (int s_ = 0; s_ < 2; s_++)
#pragma unroll
    for (int td = 0; td < 4; td++) o[s_][td] = (f32x4){0.f, 0.f, 0.f, 0.f};

  const unsigned short* kbase = kb + (size_t)b * NN * DIMD + h * DKK;
  const unsigned short* vbase = xtf + ((size_t)b * DIMD + h * DKK) * NN;
  unsigned short* Kg = Kall + grp * (64 * 68);
  unsigned short* Vg = Vall + grp * (64 * 68);
  const int jbase = grp * 1024;

  const int trow[2] = {gtid >> 3, (gtid + 256) >> 3};
  const int tcol = (gtid & 7) * 8;
  uint4 pk[2], pv[2];
#pragma unroll
  for (int r = 0; r < 2; r++) {
    pk[r] = *(const uint4*)(kbase + (size_t)(jbase + trow[r]) * DIMD + tcol);
    pv[r] = *(const uint4*)(vbase + (size_t)trow[r] * NN + jbase + tcol);
  }

  for (int itr = 0; itr < 16; itr++) {
    __syncthreads();
#pragma unroll
    for (int r = 0; r < 2; r++) {
      st8(&Kg[trow[r] * 68 + tcol], pk[r]);
      st8(&Vg[trow[r] * 68 + tcol], pv[r]);
    }
    __syncthreads();
    if (itr < 15) {
      const int j0 = jbase + (itr + 1) * 64;
#pragma unroll
      for (int r = 0; r < 2; r++) {
        pk[r] = *(const uint4*)(kbase + (size_t)(j0 + trow[r]) * DIMD + tcol);
        pv[r] = *(const uint4*)(vbase + (size_t)trow[r] * NN + j0 + tcol);
      }
    }

    __builtin_amdgcn_s_setprio(1);
#pragma unroll
    for (int t = 0; t < 4; t++) {
      bf16x8 kf0 = ld_frag(&Kg[(t * 16 + l16) * 68 + quad * 8]);
      bf16x8 kf1 = ld_frag(&Kg[(t * 16 + l16) * 68 + quad * 8 + 32]);
      f16x4 pf[2];
#pragma unroll
      for (int s_ = 0; s_ < 2; s_++) {
        f32x4 sv = (f32x4){0.f, 0.f, 0.f, 0.f};
        sv = __builtin_amdgcn_mfma_f32_16x16x32_bf16(kf0, qf[s_][0], sv, 0, 0, 0);
        sv = __builtin_amdgcn_mfma_f32_16x16x32_bf16(kf1, qf[s_][1], sv, 0, 0, 0);
        pf[s_] = sig_pack(sv);
      }
#pragma unroll
      for (int td = 0; td < 4; td++) {
        f16x4 vf = __builtin_bit_cast(
            f16x4, *(const u32x2*)&Vg[(td * 16 + l16) * 68 + t * 16 + quad * 4]);
        o[0][td] = __builtin_amdgcn_mfma_f32_16x16x16f16(vf, pf[0], o[0][td], 0, 0, 0);
        o[1][td] = __builtin_amdgcn_mfma_f32_16x16x16f16(vf, pf[1], o[1][td], 0, 0, 0);
      }
    }
    __builtin_amdgcn_s_setprio(0);
  }

  // combine the two j-groups' partial O^T through LDS; group 0 adds the
  // 0.5*rowsum(V) fold (sum of 8 race-free prep partials) and stores.
  __syncthreads();
  if (grp == 1) {
#pragma unroll
    for (int s_ = 0; s_ < 2; s_++)
#pragma unroll
      for (int td = 0; td < 4; td++) {
        int base = (wv * 32 + s_ * 16 + l16) * 66 + td * 16 + quad * 4;
        *(f32x2*)&R0[base] = (f32x2){o[s_][td][0], o[s_][td][1]};
        *(f32x2*)&R0[base + 2] = (f32x2){o[s_][td][2], o[s_][td][3]};
      }
  }
  __syncthreads();
  if (grp == 0) {
    const float* vp = vsum_p + (size_t)b * 8 * DIMD + h * DKK;
    f32x4 vs[4];
#pragma unroll
    for (int td = 0; td < 4; td++) {
      f32x4 a = (f32x4){0.f, 0.f, 0.f, 0.f};
#pragma unroll
      for (int p = 0; p < 8; p++) {
        f32x4 t = *(const f32x4*)&vp[(size_t)p * DIMD + td * 16 + quad * 4];
        a[0] += t[0]; a[1] += t[1]; a[2] += t[2]; a[3] += t[3];
      }
      vs[td] = a;
    }
#pragma unroll
    for (int s_ = 0; s_ < 2; s_++) {
#pragma unroll
      for (int td = 0; td < 4; td++) {
        int base = (wv * 32 + s_ * 16 + l16) * 66 + td * 16 + quad * 4;
        f32x2 a = *(const f32x2*)&R0[base];
        f32x2 c = *(const f32x2*)&R0[base + 2];
        o[s_][td][0] += a.x + 0.5f * vs[td][0];
        o[s_][td][1] += a.y + 0.5f * vs[td][1];
        o[s_][td][2] += c.x + 0.5f * vs[td][2];
        o[s_][td][3] += c.y + 0.5f * vs[td][3];
        float* op = out + ((size_t)b * NN + irow[s_]) * DIMD + h * DKK + td * 16 + quad * 4;
        *(f32x4*)op = o[s_][td];
      }
    }
  }
}

// ---------------------------------------------------------------------------
extern "C" void kernel_launch(void* const* d_in, const int* in_sizes, int n_in,
                              void* d_out, int out_size, void* d_ws, size_t ws_size,
                              hipStream_t stream) {
  const float* x = (const float*)d_in[0];
  const float* Wq = (const float*)d_in[1];
  const float* Wk = (const float*)d_in[2];
  const float* bias = (const float*)d_in[3]; // [1,8,1,64] flat = 512
  float* out = (float*)d_out;

  unsigned short* ws = (unsigned short*)d_ws;
  unsigned short* xtf = ws;                        // 4,194,304 (f16 bits)
  unsigned short* wtq = xtf + (size_t)MTOT * DIMD; // 262,144
  unsigned short* wtk = wtq + (size_t)DIMD * DIMD; // 262,144
  unsigned short* qb = wtk + (size_t)DIMD * DIMD;  // 4,194,304
  unsigned short* kb = qb + (size_t)MTOT * DIMD;   // 4,194,304
  float* vsum_p = (float*)(kb + (size_t)MTOT * DIMD); // [4][8][512] f32 = 64 KB

  prep<<<dim3(384), 256, 0, stream>>>(x, Wq, Wk, xtf, wtq, wtk, vsum_p);
  qk_gemm<<<dim3(64, 8), 512, 0, stream>>>(x, wtq, wtk, bias, qb, kb);
  attn<<<dim3(32, 16), 512, 0, stream>>>(qb, kb, xtf, vsum_p, out);
}